// Round 10
// baseline (723.301 us; speedup 1.0000x reference)
//
#include <hip/hip_runtime.h>
#include <math.h>

// Problem constants: B=8, planes=4, Cin=64, Cout=128, H=W=64, K=3,S=1,D=1,P=1
#define CIN   64
#define COUT  128
#define HW    4096
#define EPSF  1e-6f
#define LOG_EPS -13.815510557964274f   // logf(1e-6)
#define BLK   512

#define LDSP(p) ((__attribute__((address_space(3))) void*)(p))
#define GLBP(p) ((const __attribute__((address_space(1))) void*)(p))

// ws layout (floats): [0,576) w1n ; [576,8768) w2n^T ; [8768,16960) w2x^T ; [16960,25152) w2y^T
// (transposed [c][o] so a 16-channel chunk is 8KB CONTIGUOUS -> DMA-able via global_load_lds)
__global__ void prep_weights(const float* __restrict__ w1x, const float* __restrict__ w1y,
                             const float* __restrict__ w2x, const float* __restrict__ w2y,
                             float* __restrict__ ws) {
  __shared__ float red[256];
  const int tid = threadIdx.x;
  float s1 = 0.f, s2 = 0.f;
  for (int i = tid; i < 576; i += 256)  { float v = w1x[i] + w1y[i]; s1 += v * v; }
  for (int i = tid; i < 8192; i += 256) { float v = w2x[i] + w2y[i]; s2 += v * v; }
  red[tid] = s1; __syncthreads();
  for (int s = 128; s > 0; s >>= 1) { if (tid < s) red[tid] += red[tid + s]; __syncthreads(); }
  const float t1 = red[0]; __syncthreads();
  red[tid] = s2; __syncthreads();
  for (int s = 128; s > 0; s >>= 1) { if (tid < s) red[tid] += red[tid + s]; __syncthreads(); }
  const float t2 = red[0];
  const float r1 = 1.0f / t1, r2 = 1.0f / t2;
  for (int i = tid; i < 576; i += 256) { float v = w1x[i] + w1y[i]; ws[i] = v * v * r1; }
  for (int i = tid; i < 8192; i += 256) {
    int o = i >> 6, c = i & 63;                 // w2 is [o][c]
    float v = w2x[i] + w2y[i];
    ws[  576 + c * 128 + o] = v * v * r2;       // w2n^T  (same value formula as R1 — bit-stable)
    ws[ 8768 + c * 128 + o] = w2x[i];           // w2x^T
    ws[16960 + c * 128 + o] = w2y[i];           // w2y^T
  }
}

// ---------------- fused depthwise(3x3)+pointwise(1x1), async DMA, 2 blocks/CU ----------------
// R5 lesson: DMA fixed the memory system (FETCH 370->37MB) but 102KB LDS -> 1 block/CU -> 75% idle.
// R6: LDS = exactly 80KB (xs 2x24K dbuf + ts 16K + w2 2x8K dbuf; w1 in regs) -> 2 blocks/CU.
__global__ __launch_bounds__(BLK, 4) void fused_conv(
    const float* __restrict__ x,
    const float* __restrict__ w1x, const float* __restrict__ w1y,
    const float* __restrict__ ws,
    float* __restrict__ out) {
  const int tid   = threadIdx.x;
  const int rt    = blockIdx.x & 15;   // row tile: rows rt*4 .. rt*4+3
  const int bp    = blockIdx.x >> 4;   // b*4 + plane
  const int plane = bp & 3;
  const bool is_abs = (plane == 1);
  const float PAD = is_abs ? LOG_EPS : 0.f;
  const float* w1  = (plane < 2) ? ws          : (plane == 2 ? w1x : w1y);
  const float* w2t = (plane < 2) ? (ws + 576)  : (plane == 2 ? ws + 8768 : ws + 16960);

  // single LDS array = exactly 81920 B (no padding): xs[2] @0/6144, ts @12288, w2 bufs @16384/18432
  __shared__ float lds[20480];

  const int wav = tid >> 6;
  const int lan = tid & 63;

  // ---- x-DMA constants: 3 segs/wave; seg s covers LDS floats [s*256, s*256+256) ----
  int gch[3], goff[3]; unsigned xlb[3];
  #pragma unroll
  for (int j = 0; j < 3; ++j) {
    int s     = wav * 3 + j;
    int row16 = s * 4 + (lan >> 4);          // 0..95 = ch*6 + rr
    int ch    = row16 / 6;
    int rr    = row16 - 6 * ch;
    int gr    = rt * 4 + rr - 1;
    int grc   = gr < 0 ? 0 : (gr > 63 ? 63 : gr);                // clamped (safe) row
    int colf  = (((lan & 15) * 16) ^ ((row16 & 7) << 5)) >> 2;   // swizzled source col (both-sides swz)
    gch[j] = ch; goff[j] = grc * 64 + colf; xlb[j] = (unsigned)(s * 1024);
  }
  // w2-DMA: wave w covers floats [w*256, w*256+256) of the 2048-float chunk
  const int wsrc = wav * 256 + lan * 4;
  // fixup: lane-contiguous float4s (fixes R5's stride-12 bank pathology); 3 validity bits
  unsigned fval = 0;
  #pragma unroll
  for (int q = 0; q < 3; ++q) {
    int row16 = (3 * wav + q) * 4 + (lan >> 4);
    int rr    = row16 % 6;
    int gr    = rt * 4 + rr - 1;
    if ((unsigned)gr < 64u) fval |= (1u << q);
  }
  const bool tile_edge = (rt == 0) | (rt == 15);

  const float* xbase = x + (size_t)bp * CIN * HW;
  const int bc = tid >> 5;           // phase-B channel 0..15

  // ---- prologue: issue chunk-0 DMA (x + w2), prefetch w1 regs ----
  #pragma unroll
  for (int j = 0; j < 3; ++j)
    __builtin_amdgcn_global_load_lds(GLBP(xbase + (size_t)gch[j] * HW + goff[j]),
                                     LDSP((char*)lds + xlb[j]), 16, 0, 0);
  __builtin_amdgcn_global_load_lds(GLBP(w2t + wsrc),
                                   LDSP((char*)lds + 65536u + wav * 1024u), 16, 0, 0);
  float wreg[9];
  #pragma unroll
  for (int k = 0; k < 9; ++k) wreg[k] = w1[bc * 9 + k];

  // ---- per-phase lane mappings ----
  const int o0  = wav * 16;          // 16 outputs per wave (phase C)
  const int p0c = lan * 4;           // 4 px per lane (phase C)
  const int bl   = tid & 31;
  const int bp0  = bl * 8;           // 8 px per lane (phase B)
  const int bri  = bp0 >> 6;         // tile row 0..3
  const int bcol = bp0 & 63;         // col 0..56 step 8

  float acc[64];
  #pragma unroll
  for (int j = 0; j < 64; ++j) acc[j] = 0.f;

  #pragma unroll 1
  for (int cc = 0; cc < 4; ++cc) {
    float* Xb = lds + (cc & 1) * 6144;
    float* Wb = lds + 16384 + (cc & 1) * 2048;

    // ---- wait staging; per-wave fixup of own segments; barrier ----
    asm volatile("s_waitcnt vmcnt(0)" ::: "memory");
    if (is_abs) {
      #pragma unroll
      for (int q = 0; q < 3; ++q) {
        float4* p = (float4*)&Xb[(3 * wav + q) * 256 + lan * 4];
        float4 v = *p;
        if (fval >> q & 1u) {
          v.x = logf(v.x + EPSF); v.y = logf(v.y + EPSF);
          v.z = logf(v.z + EPSF); v.w = logf(v.w + EPSF);
        } else v = make_float4(LOG_EPS, LOG_EPS, LOG_EPS, LOG_EPS);
        *p = v;
      }
    } else if (tile_edge) {
      #pragma unroll
      for (int q = 0; q < 3; ++q)
        if (!(fval >> q & 1u))
          *(float4*)&Xb[(3 * wav + q) * 256 + lan * 4] = make_float4(0.f, 0.f, 0.f, 0.f);
    }
    asm volatile("s_waitcnt lgkmcnt(0)" ::: "memory");
    __builtin_amdgcn_s_barrier();
    __builtin_amdgcn_sched_barrier(0);

    // ---- issue next-chunk DMA into the other buffers (in flight across B + C) ----
    if (cc < 3) {
      const unsigned xb = ((cc & 1) ^ 1) * 24576u;
      #pragma unroll
      for (int j = 0; j < 3; ++j)
        __builtin_amdgcn_global_load_lds(GLBP(xbase + (size_t)((cc + 1) * 16 + gch[j]) * HW + goff[j]),
                                         LDSP((char*)lds + xb + xlb[j]), 16, 0, 0);
      __builtin_amdgcn_global_load_lds(GLBP(w2t + (cc + 1) * 2048 + wsrc),
                                       LDSP((char*)lds + 65536u + ((cc & 1) ^ 1) * 8192u + wav * 1024u), 16, 0, 0);
    }

    // ---- phase B: depthwise 3x3 -> ts (swizzled reads, w1 from regs) ----
    {
      float at[8];
      #pragma unroll
      for (int pp = 0; pp < 8; ++pp) at[pp] = 0.f;
      #pragma unroll
      for (int kr = 0; kr < 3; ++kr) {
        const int row16 = bc * 6 + bri + kr;
        const float* xr = Xb + row16 * 64;
        const int swzf  = (row16 & 7) << 3;        // float-index XOR (byte bits 5-7)
        float xv[10];
        { int il = bcol ? bcol - 1 : 0; float lv = xr[il ^ swzf]; xv[0] = bcol ? lv : PAD; }
        const int c0 = bcol ^ swzf;                // bcol 8-aligned: granule-safe
        float4 a0 = *(const float4*)(xr + c0);
        float4 a1 = *(const float4*)(xr + c0 + 4);
        xv[1] = a0.x; xv[2] = a0.y; xv[3] = a0.z; xv[4] = a0.w;
        xv[5] = a1.x; xv[6] = a1.y; xv[7] = a1.z; xv[8] = a1.w;
        { int ir = (bcol == 56) ? 63 : bcol + 8; float rv = xr[ir ^ swzf]; xv[9] = (bcol == 56) ? PAD : rv; }
        #pragma unroll
        for (int pp = 0; pp < 8; ++pp) {
          at[pp] += xv[pp]     * wreg[kr * 3 + 0];
          at[pp] += xv[pp + 1] * wreg[kr * 3 + 1];
          at[pp] += xv[pp + 2] * wreg[kr * 3 + 2];
        }
      }
      *(float4*)&lds[12288 + bc * 256 + bp0]     = make_float4(at[0], at[1], at[2], at[3]);
      *(float4*)&lds[12288 + bc * 256 + bp0 + 4] = make_float4(at[4], at[5], at[6], at[7]);
    }
    asm volatile("s_waitcnt lgkmcnt(0)" ::: "memory");
    __builtin_amdgcn_s_barrier();          // ts ready (DMA still in flight — no vmcnt here)
    __builtin_amdgcn_sched_barrier(0);

    // ---- phase C: pointwise GEMM accumulate ----
    #pragma unroll
    for (int k = 0; k < 16; ++k) {
      float4 tq = *(const float4*)&lds[12288 + k * 256 + p0c];   // contiguous 1KB/wave, minimal
      #pragma unroll
      for (int g = 0; g < 4; ++g) {
        float4 wv4 = *(const float4*)&Wb[k * 128 + o0 + g * 4];  // wave-broadcast
        acc[(g*4+0)*4+0] += wv4.x*tq.x; acc[(g*4+0)*4+1] += wv4.x*tq.y;
        acc[(g*4+0)*4+2] += wv4.x*tq.z; acc[(g*4+0)*4+3] += wv4.x*tq.w;
        acc[(g*4+1)*4+0] += wv4.y*tq.x; acc[(g*4+1)*4+1] += wv4.y*tq.y;
        acc[(g*4+1)*4+2] += wv4.y*tq.z; acc[(g*4+1)*4+3] += wv4.y*tq.w;
        acc[(g*4+2)*4+0] += wv4.z*tq.x; acc[(g*4+2)*4+1] += wv4.z*tq.y;
        acc[(g*4+2)*4+2] += wv4.z*tq.z; acc[(g*4+2)*4+3] += wv4.z*tq.w;
        acc[(g*4+3)*4+0] += wv4.w*tq.x; acc[(g*4+3)*4+1] += wv4.w*tq.y;
        acc[(g*4+3)*4+2] += wv4.w*tq.z; acc[(g*4+3)*4+3] += wv4.w*tq.w;
      }
    }
    // ---- prefetch w1 regs for next chunk (drained by next loop-top vmcnt(0)) ----
    if (cc < 3) {
      #pragma unroll
      for (int k = 0; k < 9; ++k) wreg[k] = w1[((cc + 1) * 16 + bc) * 9 + k];
    }
    // loop-top barrier of next iter orders C's ts/Wb reads vs next writes
  }

  // ---- epilogue: (optional exp) + coalesced float4 stores ----
  float* obase = out + (size_t)bp * COUT * HW + rt * 256 + p0c;
  #pragma unroll
  for (int jj = 0; jj < 16; ++jj) {
    float4 v = make_float4(acc[jj*4], acc[jj*4+1], acc[jj*4+2], acc[jj*4+3]);
    if (is_abs) { v.x = expf(v.x); v.y = expf(v.y); v.z = expf(v.z); v.w = expf(v.w); }
    *(float4*)(obase + (size_t)(o0 + jj) * HW) = v;
  }
}

extern "C" void kernel_launch(void* const* d_in, const int* in_sizes, int n_in,
                              void* d_out, int out_size, void* d_ws, size_t ws_size,
                              hipStream_t stream) {
  const float* x   = (const float*)d_in[0];
  const float* w1x = (const float*)d_in[1];
  const float* w1y = (const float*)d_in[2];
  const float* w2x = (const float*)d_in[3];
  const float* w2y = (const float*)d_in[4];
  float* out = (float*)d_out;
  float* ws  = (float*)d_ws;   // needs 25152 floats = 100.6 KB

  prep_weights<<<1, 256, 0, stream>>>(w1x, w1y, w2x, w2y, ws);
  fused_conv<<<512, BLK, 0, stream>>>(x, w1x, w1y, ws, out);
}

// Round 11
// 400.736 us; speedup vs baseline: 1.8049x; 1.8049x over previous
//
#include <hip/hip_runtime.h>
#include <math.h>

// Problem constants: B=8, planes=4, Cin=64, Cout=128, H=W=64, K=3,S=1,D=1,P=1
#define CIN   64
#define COUT  128
#define HW    4096
#define EPSF  1e-6f
#define LOG_EPS -13.815510557964274f   // logf(1e-6)
#define BLK   512

#define LDSP(p) ((__attribute__((address_space(3))) void*)(p))
#define GLBP(p) ((const __attribute__((address_space(1))) void*)(p))

// ws layout (floats): [0,576) w1n ; [576,8768) w2n^T ; [8768,16960) w2x^T ; [16960,25152) w2y^T
// (transposed [c][o] so a 16-channel chunk is 8KB CONTIGUOUS -> DMA-able via global_load_lds)
__global__ void prep_weights(const float* __restrict__ w1x, const float* __restrict__ w1y,
                             const float* __restrict__ w2x, const float* __restrict__ w2y,
                             float* __restrict__ ws) {
  __shared__ float red[256];
  const int tid = threadIdx.x;
  float s1 = 0.f, s2 = 0.f;
  for (int i = tid; i < 576; i += 256)  { float v = w1x[i] + w1y[i]; s1 += v * v; }
  for (int i = tid; i < 8192; i += 256) { float v = w2x[i] + w2y[i]; s2 += v * v; }
  red[tid] = s1; __syncthreads();
  for (int s = 128; s > 0; s >>= 1) { if (tid < s) red[tid] += red[tid + s]; __syncthreads(); }
  const float t1 = red[0]; __syncthreads();
  red[tid] = s2; __syncthreads();
  for (int s = 128; s > 0; s >>= 1) { if (tid < s) red[tid] += red[tid + s]; __syncthreads(); }
  const float t2 = red[0];
  const float r1 = 1.0f / t1, r2 = 1.0f / t2;
  for (int i = tid; i < 576; i += 256) { float v = w1x[i] + w1y[i]; ws[i] = v * v * r1; }
  for (int i = tid; i < 8192; i += 256) {
    int o = i >> 6, c = i & 63;                 // w2 is [o][c]
    float v = w2x[i] + w2y[i];
    ws[  576 + c * 128 + o] = v * v * r2;       // w2n^T  (same value formula as R1 — bit-stable)
    ws[ 8768 + c * 128 + o] = w2x[i];           // w2x^T
    ws[16960 + c * 128 + o] = w2y[i];           // w2y^T
  }
}

// ---------------- fused depthwise(3x3)+pointwise(1x1), async DMA ----------------
// VGPR-cap ledger (pool = 512 VGPR/SIMD; 512-thr block = 2 waves/SIMD):
//   (512,4) -> cap 128 -> SPILLS (R3: 600us, R10: 643us; FETCH/WRITE explode, VALUBusy ~4%)
//   (512,2) -> cap 256 -> allocator lands ~128, CLEAN (R5: FETCH 37MB)
// NEVER set (512,4) on this body. 80KB LDS allows 2 blocks/CU iff actual VGPR <= 128.
__global__ __launch_bounds__(BLK, 2) void fused_conv(
    const float* __restrict__ x,
    const float* __restrict__ w1x, const float* __restrict__ w1y,
    const float* __restrict__ ws,
    float* __restrict__ out) {
  const int tid   = threadIdx.x;
  const int rt    = blockIdx.x & 15;   // row tile: rows rt*4 .. rt*4+3
  const int bp    = blockIdx.x >> 4;   // b*4 + plane
  const int plane = bp & 3;
  const bool is_abs = (plane == 1);
  const float PAD = is_abs ? LOG_EPS : 0.f;
  const float* w1  = (plane < 2) ? ws          : (plane == 2 ? w1x : w1y);
  const float* w2t = (plane < 2) ? (ws + 576)  : (plane == 2 ? ws + 8768 : ws + 16960);

  // single LDS array = exactly 81920 B (no padding): xs[2] @0/6144, ts @12288, w2 bufs @16384/18432
  __shared__ float lds[20480];

  const int wav = tid >> 6;
  const int lan = tid & 63;

  // ---- x-DMA constants: 3 segs/wave; seg s covers LDS floats [s*256, s*256+256) ----
  int gch[3], goff[3]; unsigned xlb[3];
  #pragma unroll
  for (int j = 0; j < 3; ++j) {
    int s     = wav * 3 + j;
    int row16 = s * 4 + (lan >> 4);          // 0..95 = ch*6 + rr
    int ch    = row16 / 6;
    int rr    = row16 - 6 * ch;
    int gr    = rt * 4 + rr - 1;
    int grc   = gr < 0 ? 0 : (gr > 63 ? 63 : gr);                // clamped (safe) row
    int colf  = (((lan & 15) * 16) ^ ((row16 & 7) << 5)) >> 2;   // swizzled source col (both-sides swz)
    gch[j] = ch; goff[j] = grc * 64 + colf; xlb[j] = (unsigned)(s * 1024);
  }
  // w2-DMA: wave w covers floats [w*256, w*256+256) of the 2048-float chunk
  const int wsrc = wav * 256 + lan * 4;
  // fixup: lane-contiguous float4s; 3 validity bits
  unsigned fval = 0;
  #pragma unroll
  for (int q = 0; q < 3; ++q) {
    int row16 = (3 * wav + q) * 4 + (lan >> 4);
    int rr    = row16 % 6;
    int gr    = rt * 4 + rr - 1;
    if ((unsigned)gr < 64u) fval |= (1u << q);
  }
  const bool tile_edge = (rt == 0) | (rt == 15);

  const float* xbase = x + (size_t)bp * CIN * HW;
  const int bc = tid >> 5;           // phase-B channel 0..15

  // ---- prologue: issue chunk-0 DMA (x + w2), prefetch w1 regs ----
  #pragma unroll
  for (int j = 0; j < 3; ++j)
    __builtin_amdgcn_global_load_lds(GLBP(xbase + (size_t)gch[j] * HW + goff[j]),
                                     LDSP((char*)lds + xlb[j]), 16, 0, 0);
  __builtin_amdgcn_global_load_lds(GLBP(w2t + wsrc),
                                   LDSP((char*)lds + 65536u + wav * 1024u), 16, 0, 0);
  float wreg[9];
  #pragma unroll
  for (int k = 0; k < 9; ++k) wreg[k] = w1[bc * 9 + k];

  // ---- per-phase lane mappings ----
  const int o0  = wav * 16;          // 16 outputs per wave (phase C)
  const int p0c = lan * 4;           // 4 px per lane (phase C)
  const int bl   = tid & 31;
  const int bp0  = bl * 8;           // 8 px per lane (phase B)
  const int bri  = bp0 >> 6;         // tile row 0..3
  const int bcol = bp0 & 63;         // col 0..56 step 8

  float acc[64];
  #pragma unroll
  for (int j = 0; j < 64; ++j) acc[j] = 0.f;

  #pragma unroll 1
  for (int cc = 0; cc < 4; ++cc) {
    float* Xb = lds + (cc & 1) * 6144;
    float* Wb = lds + 16384 + (cc & 1) * 2048;

    // ---- wait staging; per-wave fixup of own segments; barrier ----
    asm volatile("s_waitcnt vmcnt(0)" ::: "memory");
    if (is_abs) {
      #pragma unroll
      for (int q = 0; q < 3; ++q) {
        float4* p = (float4*)&Xb[(3 * wav + q) * 256 + lan * 4];
        float4 v = *p;
        if (fval >> q & 1u) {
          v.x = logf(v.x + EPSF); v.y = logf(v.y + EPSF);
          v.z = logf(v.z + EPSF); v.w = logf(v.w + EPSF);
        } else v = make_float4(LOG_EPS, LOG_EPS, LOG_EPS, LOG_EPS);
        *p = v;
      }
    } else if (tile_edge) {
      #pragma unroll
      for (int q = 0; q < 3; ++q)
        if (!(fval >> q & 1u))
          *(float4*)&Xb[(3 * wav + q) * 256 + lan * 4] = make_float4(0.f, 0.f, 0.f, 0.f);
    }
    asm volatile("s_waitcnt lgkmcnt(0)" ::: "memory");
    __builtin_amdgcn_s_barrier();
    __builtin_amdgcn_sched_barrier(0);

    // ---- issue next-chunk DMA into the other buffers (in flight across B + C) ----
    if (cc < 3) {
      const unsigned xb = ((cc & 1) ^ 1) * 24576u;
      #pragma unroll
      for (int j = 0; j < 3; ++j)
        __builtin_amdgcn_global_load_lds(GLBP(xbase + (size_t)((cc + 1) * 16 + gch[j]) * HW + goff[j]),
                                         LDSP((char*)lds + xb + xlb[j]), 16, 0, 0);
      __builtin_amdgcn_global_load_lds(GLBP(w2t + (cc + 1) * 2048 + wsrc),
                                       LDSP((char*)lds + 65536u + ((cc & 1) ^ 1) * 8192u + wav * 1024u), 16, 0, 0);
    }

    // ---- phase B: depthwise 3x3 -> ts (swizzled reads, w1 from regs) ----
    {
      float at[8];
      #pragma unroll
      for (int pp = 0; pp < 8; ++pp) at[pp] = 0.f;
      #pragma unroll
      for (int kr = 0; kr < 3; ++kr) {
        const int row16 = bc * 6 + bri + kr;
        const float* xr = Xb + row16 * 64;
        const int swzf  = (row16 & 7) << 3;        // float-index XOR (byte bits 5-7)
        float xv[10];
        { int il = bcol ? bcol - 1 : 0; float lv = xr[il ^ swzf]; xv[0] = bcol ? lv : PAD; }
        const int c0 = bcol ^ swzf;                // bcol 8-aligned: granule-safe
        float4 a0 = *(const float4*)(xr + c0);
        float4 a1 = *(const float4*)(xr + c0 + 4);
        xv[1] = a0.x; xv[2] = a0.y; xv[3] = a0.z; xv[4] = a0.w;
        xv[5] = a1.x; xv[6] = a1.y; xv[7] = a1.z; xv[8] = a1.w;
        { int ir = (bcol == 56) ? 63 : bcol + 8; float rv = xr[ir ^ swzf]; xv[9] = (bcol == 56) ? PAD : rv; }
        #pragma unroll
        for (int pp = 0; pp < 8; ++pp) {
          at[pp] += xv[pp]     * wreg[kr * 3 + 0];
          at[pp] += xv[pp + 1] * wreg[kr * 3 + 1];
          at[pp] += xv[pp + 2] * wreg[kr * 3 + 2];
        }
      }
      *(float4*)&lds[12288 + bc * 256 + bp0]     = make_float4(at[0], at[1], at[2], at[3]);
      *(float4*)&lds[12288 + bc * 256 + bp0 + 4] = make_float4(at[4], at[5], at[6], at[7]);
    }
    asm volatile("s_waitcnt lgkmcnt(0)" ::: "memory");
    __builtin_amdgcn_s_barrier();          // ts ready (DMA still in flight — no vmcnt here)
    __builtin_amdgcn_sched_barrier(0);

    // ---- phase C: pointwise GEMM accumulate ----
    #pragma unroll
    for (int k = 0; k < 16; ++k) {
      float4 tq = *(const float4*)&lds[12288 + k * 256 + p0c];   // contiguous 1KB/wave, minimal
      #pragma unroll
      for (int g = 0; g < 4; ++g) {
        float4 wv4 = *(const float4*)&Wb[k * 128 + o0 + g * 4];  // wave-broadcast
        acc[(g*4+0)*4+0] += wv4.x*tq.x; acc[(g*4+0)*4+1] += wv4.x*tq.y;
        acc[(g*4+0)*4+2] += wv4.x*tq.z; acc[(g*4+0)*4+3] += wv4.x*tq.w;
        acc[(g*4+1)*4+0] += wv4.y*tq.x; acc[(g*4+1)*4+1] += wv4.y*tq.y;
        acc[(g*4+1)*4+2] += wv4.y*tq.z; acc[(g*4+1)*4+3] += wv4.y*tq.w;
        acc[(g*4+2)*4+0] += wv4.z*tq.x; acc[(g*4+2)*4+1] += wv4.z*tq.y;
        acc[(g*4+2)*4+2] += wv4.z*tq.z; acc[(g*4+2)*4+3] += wv4.z*tq.w;
        acc[(g*4+3)*4+0] += wv4.w*tq.x; acc[(g*4+3)*4+1] += wv4.w*tq.y;
        acc[(g*4+3)*4+2] += wv4.w*tq.z; acc[(g*4+3)*4+3] += wv4.w*tq.w;
      }
    }
    // ---- prefetch w1 regs for next chunk (drained by next loop-top vmcnt(0)) ----
    if (cc < 3) {
      #pragma unroll
      for (int k = 0; k < 9; ++k) wreg[k] = w1[((cc + 1) * 16 + bc) * 9 + k];
    }
    // loop-top barrier of next iter orders C's ts/Wb reads vs next writes
  }

  // ---- epilogue: (optional exp) + coalesced float4 stores ----
  float* obase = out + (size_t)bp * COUT * HW + rt * 256 + p0c;
  #pragma unroll
  for (int jj = 0; jj < 16; ++jj) {
    float4 v = make_float4(acc[jj*4], acc[jj*4+1], acc[jj*4+2], acc[jj*4+3]);
    if (is_abs) { v.x = expf(v.x); v.y = expf(v.y); v.z = expf(v.z); v.w = expf(v.w); }
    *(float4*)(obase + (size_t)(o0 + jj) * HW) = v;
  }
}

extern "C" void kernel_launch(void* const* d_in, const int* in_sizes, int n_in,
                              void* d_out, int out_size, void* d_ws, size_t ws_size,
                              hipStream_t stream) {
  const float* x   = (const float*)d_in[0];
  const float* w1x = (const float*)d_in[1];
  const float* w1y = (const float*)d_in[2];
  const float* w2x = (const float*)d_in[3];
  const float* w2y = (const float*)d_in[4];
  float* out = (float*)d_out;
  float* ws  = (float*)d_ws;   // needs 25152 floats = 100.6 KB

  prep_weights<<<1, 256, 0, stream>>>(w1x, w1y, w2x, w2y, ws);
  fused_conv<<<512, BLK, 0, stream>>>(x, w1x, w1y, ws, out);
}